// Round 21
// baseline (37.617 us; speedup 1.0000x reference)
//
#include <hip/hip_runtime.h>

typedef __bf16 bf16_t;
typedef __bf16 bf16x4 __attribute__((ext_vector_type(4)));
typedef __bf16 bf16x8 __attribute__((ext_vector_type(8)));
typedef float  f32x4  __attribute__((ext_vector_type(4)));

#define B_SZ  16
#define L_SEQ 2048
#define D_H   64
#define QB    64
#define KB    128

// softmax is over (S/8); fold log2(e)/8 into Q so MFMA output is in log2 units
#define QSCALE 0.18033688011112043f

// ws: Opart[512 slots][64*64] f32 (8 MB) | MLb[512][128] (m:0..63, l:64..127)
#define OPART_FL ((size_t)512 * QB * D_H)
#define ML_FL    ((size_t)512 * 128)

// ---------------- producer/consumer + pair K-split kernel ----------------
// pair p (0..15): tileL qt=31-p (nktL=(33-p)>>1 in 9..16), tileS qt=p (nktS=(p+2)>>1), sum 17.
// role 0 (front): positions 0..8 (9 iters, all tileL) -> tileL partial
// role 1 (back):  positions 9..16 (8 iters: tileL tail + all tileS) -> tileL partial + tileS direct
// waves 0-3: consumers (r20 compute engine); waves 4-7: producers (r20 staging engine).
__global__ __launch_bounds__(512, 4)
void attn_pcs_kernel(const float* __restrict__ Qg, const float* __restrict__ Kg,
                     const float* __restrict__ Vg, float* __restrict__ Og,
                     float* __restrict__ Opart, float* __restrict__ MLb)
{
    const int lin  = blockIdx.x;          // 0..511
    const int xcd  = lin & 7;
    const int b    = xcd * 2 + ((lin >> 3) & 1);   // 2 batches per XCD
    const int p    = (lin >> 4) & 15;
    const int role = lin >> 8;            // both roles of a pair on the same XCD
    const int pair = b * 16 + p;

    const int nktL = (33 - p) >> 1;       // 9..16
    const int cnt1 = role ? (nktL - 9) : 9;
    const int total = role ? 8 : 9;

    const int tid  = threadIdx.x;
    const int wave = tid >> 6;            // 0..7
    const int lane = tid & 63;
    const int lg   = lane >> 4;
    const int lc   = lane & 15;

    __shared__ __align__(16) bf16_t K_lds[2][KB][72];      // 36 KB
    __shared__ __align__(16) bf16_t Vt_lds[2][D_H][136];   // 34 KB

    const size_t bbase = (size_t)b * L_SEQ * D_H;

    auto seqKt = [&](int j) {
        const int pos = role * 9 + j;
        return pos < nktL ? pos : pos - nktL;
    };

    if (wave >= 4) {
        // ================= PRODUCER (waves 4-7, 256 threads) =================
        const int pt   = tid - 256;
        const int vkb  = pt & 31;
        const int vdg  = pt >> 5;
        const int vpos = ((vkb >> 3) << 5) + ((vkb & 3) << 3) + (((vkb >> 2) & 1) << 2);

        f32x4 kreg[8], vreg[8];

        auto issueK = [&](int kt) {
            const int kbase = kt * KB;
#pragma unroll
            for (int i = 0; i < 8; ++i) {
                const int f = i * 256 + pt;
                const int r = f >> 4, c4 = (f & 15) * 4;
                kreg[i] = *reinterpret_cast<const f32x4*>(Kg + bbase + (size_t)(kbase + r) * D_H + c4);
            }
        };
        auto issueV = [&](int kt) {
            const int kbase = kt * KB;
#pragma unroll
            for (int d2 = 0; d2 < 2; ++d2)
#pragma unroll
                for (int i = 0; i < 4; ++i)
                    vreg[d2 * 4 + i] = *reinterpret_cast<const f32x4*>(
                        Vg + bbase + (size_t)(kbase + vkb * 4 + i) * D_H + (vdg + d2 * 8) * 4);
        };
        auto writeK = [&](int buf) {
#pragma unroll
            for (int i = 0; i < 8; ++i) {
                const int f = i * 256 + pt;
                const int r = f >> 4, c4 = (f & 15) * 4;
                bf16x4 k4 = { (bf16_t)kreg[i][0], (bf16_t)kreg[i][1], (bf16_t)kreg[i][2], (bf16_t)kreg[i][3] };
                *reinterpret_cast<bf16x4*>(&K_lds[buf][r][c4]) = k4;
            }
        };
        auto writeV = [&](int buf) {
#pragma unroll
            for (int d2 = 0; d2 < 2; ++d2) {
                const int db = vdg + d2 * 8;
#pragma unroll
                for (int j = 0; j < 4; ++j) {
                    bf16x4 cj = { (bf16_t)vreg[d2 * 4 + 0][j], (bf16_t)vreg[d2 * 4 + 1][j],
                                  (bf16_t)vreg[d2 * 4 + 2][j], (bf16_t)vreg[d2 * 4 + 3][j] };
                    *reinterpret_cast<bf16x4*>(&Vt_lds[buf][db * 4 + j][vpos]) = cj;
                }
            }
        };

        issueK(seqKt(0)); issueV(seqKt(0)); writeK(0); writeV(0);
        __syncthreads();                                   // prologue
        for (int j = 0; j < total; ++j) {
            if (j + 1 < total) {
                const int nk = seqKt(j + 1);
                issueK(nk); issueV(nk);
                writeK((j + 1) & 1); writeV((j + 1) & 1);
            }
            __syncthreads();
        }
    } else {
        // ================= CONSUMER (waves 0-3) =================
        bf16x8 qa[2];
        int qrow;
        auto loadQ = [&](int qt_) {
            qrow = qt_ * QB + wave * 16 + lc;
#pragma unroll
            for (int h = 0; h < 2; ++h) {
                const float* qp = Qg + bbase + (size_t)qrow * D_H + h * 32 + lg * 8;
                const f32x4 f0 = *reinterpret_cast<const f32x4*>(qp);
                const f32x4 f1 = *reinterpret_cast<const f32x4*>(qp + 4);
                bf16x8 a;
#pragma unroll
                for (int j = 0; j < 4; ++j) { a[j] = (bf16_t)(f0[j] * QSCALE); a[4 + j] = (bf16_t)(f1[j] * QSCALE); }
                qa[h] = a;
            }
        };

        loadQ(31 - p);                    // tileL first (may be empty for role1,p=15)

        f32x4 o[4];
#pragma unroll
        for (int dt = 0; dt < 4; ++dt) o[dt] = (f32x4){0.f, 0.f, 0.f, 0.f};
        float m = -1e30f, l = 0.f;        // per-lane l partial in frame m

        auto writePartialL = [&]() {
            float lr = l;
            lr += __shfl_xor(lr, 16);
            lr += __shfl_xor(lr, 32);
            const int slot = pair * 2 + role;
            float* ob = Opart + (size_t)slot * (QB * D_H);
            const int qL = wave * 16 + lc;   // 0..63
#pragma unroll
            for (int dt = 0; dt < 4; ++dt)
                *reinterpret_cast<f32x4*>(&ob[qL * 64 + dt * 16 + lg * 4]) = o[dt];
            if (lg == 0) { MLb[slot * 128 + qL] = m; MLb[slot * 128 + 64 + qL] = lr; }
        };

        __syncthreads();                                   // prologue
        for (int j = 0; j < total; ++j) {
            if (role && j == cnt1) {
                // commit tileL partial (possibly empty), switch to tileS
                writePartialL();
                loadQ(p);
#pragma unroll
                for (int dt = 0; dt < 4; ++dt) o[dt] = (f32x4){0.f, 0.f, 0.f, 0.f};
                m = -1e30f; l = 0.f;
            }
            const int pos = role * 9 + j;
            const int kt  = pos < nktL ? pos : pos - nktL;
            const int kb0 = kt * KB;
            const int cur = j & 1;

            // ---- S^T = K Q^T (log2 units) ----
            f32x4 sc[8];
            __builtin_amdgcn_s_setprio(1);
#pragma unroll
            for (int n = 0; n < 8; ++n) {
                f32x4 acc = (f32x4){0.f, 0.f, 0.f, 0.f};
#pragma unroll
                for (int h = 0; h < 2; ++h) {
                    const bf16x8 kb = *reinterpret_cast<const bf16x8*>(&K_lds[cur][n * 16 + lc][h * 32 + lg * 8]);
                    acc = __builtin_amdgcn_mfma_f32_16x16x32_bf16(kb, qa[h], acc, 0, 0, 0);
                }
                sc[n] = acc;
            }
            __builtin_amdgcn_s_setprio(0);

            const bool diag = (pos == nktL - 1) || (pos == 16);   // last chunk of L or S
            if (diag) {
#pragma unroll
                for (int n = 0; n < 8; ++n)
#pragma unroll
                    for (int r = 0; r < 4; ++r)
                        if (kb0 + n * 16 + lg * 4 + r > qrow) sc[n][r] = -1e30f;
            }

            // ---- defer-max online softmax (per-lane; cross-lane only on slow path) ----
            float mxp = fmaxf(fmaxf(sc[0][0], sc[0][1]), fmaxf(sc[0][2], sc[0][3]));
#pragma unroll
            for (int n = 1; n < 8; ++n)
                mxp = fmaxf(mxp, fmaxf(fmaxf(sc[n][0], sc[n][1]), fmaxf(sc[n][2], sc[n][3])));
            if (!__all(mxp <= m + 8.0f)) {
                float mx = mxp;
                mx = fmaxf(mx, __shfl_xor(mx, 16));
                mx = fmaxf(mx, __shfl_xor(mx, 32));
                const float mn = fmaxf(m, mx);
                const float alpha = exp2f(m - mn);
                m = mn;
                l *= alpha;
#pragma unroll
                for (int dt = 0; dt < 4; ++dt)
#pragma unroll
                    for (int r = 0; r < 4; ++r) o[dt][r] *= alpha;
            }
            bf16x8 w[4];
            float rs = 0.f;
#pragma unroll
            for (int n = 0; n < 8; ++n) {
                const float p0 = exp2f(sc[n][0] - m), p1 = exp2f(sc[n][1] - m);
                const float p2 = exp2f(sc[n][2] - m), p3 = exp2f(sc[n][3] - m);
                rs += (p0 + p1) + (p2 + p3);
                const int wi = n >> 1, off = (n & 1) * 4;
                w[wi][off + 0] = (bf16_t)p0; w[wi][off + 1] = (bf16_t)p1;
                w[wi][off + 2] = (bf16_t)p2; w[wi][off + 3] = (bf16_t)p3;
            }
            l += rs;

            // ---- O^T += V^T P ----
            __builtin_amdgcn_s_setprio(1);
#pragma unroll
            for (int ks = 0; ks < 4; ++ks) {
#pragma unroll
                for (int dt = 0; dt < 4; ++dt) {
                    const bf16x8 vb = *reinterpret_cast<const bf16x8*>(&Vt_lds[cur][dt * 16 + lc][ks * 32 + lg * 8]);
                    o[dt] = __builtin_amdgcn_mfma_f32_16x16x32_bf16(vb, w[ks], o[dt], 0, 0, 0);
                }
            }
            __builtin_amdgcn_s_setprio(0);

            __syncthreads();
        }

        if (role == 0) {
            writePartialL();                     // front: tileL partial only
        } else {
            // back: tileS complete -> divide and write directly
            float lr = l;
            lr += __shfl_xor(lr, 16);
            lr += __shfl_xor(lr, 32);
            const float inv = 1.0f / lr;
#pragma unroll
            for (int dt = 0; dt < 4; ++dt) {
                f32x4 val = { o[dt][0] * inv, o[dt][1] * inv, o[dt][2] * inv, o[dt][3] * inv };
                *reinterpret_cast<f32x4*>(Og + bbase + (size_t)qrow * D_H + dt * 16 + lg * 4) = val;
            }
        }
    }
}

// ---------------- merge: combine the two tileL partials per (b, p) ----------------
__global__ __launch_bounds__(256)
void merge_kernel(const float* __restrict__ Opart, const float* __restrict__ MLb,
                  float* __restrict__ Og)
{
    const int pairIdx = blockIdx.x;      // 0..255 (= b*16 + p)
    const int b  = pairIdx >> 4, p = pairIdx & 15;
    const int qt = 31 - p;
    const int t  = threadIdx.x;
    const int q  = t >> 2;               // 0..63
    const int dc = (t & 3) << 4;         // 0,16,32,48

    const int slot0 = pairIdx * 2, slot1 = slot0 + 1;
    const float m0 = MLb[slot0 * 128 + q], l0 = MLb[slot0 * 128 + 64 + q];
    const float m1 = MLb[slot1 * 128 + q], l1 = MLb[slot1 * 128 + 64 + q];
    const float mt = fmaxf(m0, m1);
    const float a0 = exp2f(m0 - mt), a1 = exp2f(m1 - mt);
    const float inv = 1.0f / (l0 * a0 + l1 * a1);

    const float* o0 = Opart + (size_t)slot0 * (QB * D_H) + q * 64 + dc;
    const float* o1 = Opart + (size_t)slot1 * (QB * D_H) + q * 64 + dc;
    float* og = Og + (size_t)b * L_SEQ * D_H + (size_t)(qt * QB + q) * D_H + dc;
#pragma unroll
    for (int i = 0; i < 4; ++i) {
        const f32x4 v0 = *reinterpret_cast<const f32x4*>(o0 + i * 4);
        const f32x4 v1 = *reinterpret_cast<const f32x4*>(o1 + i * 4);
        f32x4 r;
#pragma unroll
        for (int k = 0; k < 4; ++k) r[k] = (v0[k] * a0 + v1[k] * a1) * inv;
        *reinterpret_cast<f32x4*>(og + i * 4) = r;
    }
}

// ---------------- fallback: round-20 producer/consumer kernel (no ws needed) ----------------
__global__ __launch_bounds__(512, 4)
void attn_pc_kernel(const float* __restrict__ Qg, const float* __restrict__ Kg,
                    const float* __restrict__ Vg, float* __restrict__ Og)
{
    const int lin  = blockIdx.x;
    const int xcd  = lin & 7;
    const int slot = lin >> 3;
    const int half = slot >> 5;
    const int qi   = slot & 31;
    const int b    = xcd * 2 + half;
    const int qt   = half ? qi : (31 - qi);

    const int tid  = threadIdx.x;
    const int wave = tid >> 6;
    const int lane = tid & 63;
    const int lg   = lane >> 4;
    const int lc   = lane & 15;

    __shared__ __align__(16) bf16_t K_lds[2][KB][72];
    __shared__ __align__(16) bf16_t Vt_lds[2][D_H][136];

    const size_t bbase = (size_t)b * L_SEQ * D_H;
    const int nkt = (qt + 2) >> 1;

    if (wave >= 4) {
        const int pt   = tid - 256;
        const int vkb  = pt & 31;
        const int vdg  = pt >> 5;
        const int vpos = ((vkb >> 3) << 5) + ((vkb & 3) << 3) + (((vkb >> 2) & 1) << 2);

        f32x4 kreg[8], vreg[8];
        auto issueK = [&](int kt) {
            const int kbase = kt * KB;
#pragma unroll
            for (int i = 0; i < 8; ++i) {
                const int f = i * 256 + pt;
                const int r = f >> 4, c4 = (f & 15) * 4;
                kreg[i] = *reinterpret_cast<const f32x4*>(Kg + bbase + (size_t)(kbase + r) * D_H + c4);
            }
        };
        auto issueV = [&](int kt) {
            const int kbase = kt * KB;
#pragma unroll
            for (int d2 = 0; d2 < 2; ++d2)
#pragma unroll
                for (int i = 0; i < 4; ++i)
                    vreg[d2 * 4 + i] = *reinterpret_cast<const f32x4*>(
                        Vg + bbase + (size_t)(kbase + vkb * 4 + i) * D_H + (vdg + d2 * 8) * 4);
        };
        auto writeK = [&](int buf) {
#pragma unroll
            for (int i = 0; i < 8; ++i) {
                const int f = i * 256 + pt;
                const int r = f >> 4, c4 = (f & 15) * 4;
                bf16x4 k4 = { (bf16_t)kreg[i][0], (bf16_t)kreg[i][1], (bf16_t)kreg[i][2], (bf16_t)kreg[i][3] };
                *reinterpret_cast<bf16x4*>(&K_lds[buf][r][c4]) = k4;
            }
        };
        auto writeV = [&](int buf) {
#pragma unroll
            for (int d2 = 0; d2 < 2; ++d2) {
                const int db = vdg + d2 * 8;
#pragma unroll
                for (int j = 0; j < 4; ++j) {
                    bf16x4 cj = { (bf16_t)vreg[d2 * 4 + 0][j], (bf16_t)vreg[d2 * 4 + 1][j],
                                  (bf16_t)vreg[d2 * 4 + 2][j], (bf16_t)vreg[d2 * 4 + 3][j] };
                    *reinterpret_cast<bf16x4*>(&Vt_lds[buf][db * 4 + j][vpos]) = cj;
                }
            }
        };

        issueK(0); issueV(0); writeK(0); writeV(0);
        __syncthreads();
        for (int kt = 0; kt < nkt; ++kt) {
            if (kt + 1 < nkt) {
                issueK(kt + 1); issueV(kt + 1);
                writeK((kt + 1) & 1); writeV((kt + 1) & 1);
            }
            __syncthreads();
        }
    } else {
        const int qrow = qt * QB + wave * 16 + lc;
        bf16x8 qa[2];
#pragma unroll
        for (int h = 0; h < 2; ++h) {
            const float* qp = Qg + bbase + (size_t)qrow * D_H + h * 32 + lg * 8;
            const f32x4 f0 = *reinterpret_cast<const f32x4*>(qp);
            const f32x4 f1 = *reinterpret_cast<const f32x4*>(qp + 4);
            bf16x8 a;
#pragma unroll
            for (int j = 0; j < 4; ++j) { a[j] = (bf16_t)(f0[j] * QSCALE); a[4 + j] = (bf16_t)(f1[j] * QSCALE); }
            qa[h] = a;
        }
        f32x4 o[4];
#pragma unroll
        for (int dt = 0; dt < 4; ++dt) o[dt] = (f32x4){0.f, 0.f, 0.f, 0.f};
        float m = -1e30f, l = 0.f;

        __syncthreads();
        for (int kt = 0; kt < nkt; ++kt) {
            const bool last = (kt == nkt - 1);
            const int kbase = kt * KB;
            const int cur   = kt & 1;
            f32x4 sc[8];
            __builtin_amdgcn_s_setprio(1);
#pragma unroll
            for (int n = 0; n < 8; ++n) {
                f32x4 acc = (f32x4){0.f, 0.f, 0.f, 0.f};
#pragma unroll
                for (int h = 0; h < 2; ++h) {
                    const bf16x8 kb = *reinterpret_cast<const bf16x8*>(&K_lds[cur][n * 16 + lc][h * 32 + lg * 8]);
                    acc = __builtin_amdgcn_mfma_f32_16x16x32_bf16(kb, qa[h], acc, 0, 0, 0);
                }
                sc[n] = acc;
            }
            __builtin_amdgcn_s_setprio(0);
            if (last) {
#pragma unroll
                for (int n = 0; n < 8; ++n)
#pragma unroll
                    for (int r = 0; r < 4; ++r)
                        if (kbase + n * 16 + lg * 4 + r > qrow) sc[n][r] = -1e30f;
            }
            float mxp = fmaxf(fmaxf(sc[0][0], sc[0][1]), fmaxf(sc[0][2], sc[0][3]));
#pragma unroll
            for (int n = 1; n < 8; ++n)
                mxp = fmaxf(mxp, fmaxf(fmaxf(sc[n][0], sc[n][1]), fmaxf(sc[n][2], sc[n][3])));
            if (!__all(mxp <= m + 8.0f)) {
                float mx = mxp;
                mx = fmaxf(mx, __shfl_xor(mx, 16));
                mx = fmaxf(mx, __shfl_xor(mx, 32));
                const float mn = fmaxf(m, mx);
                const float alpha = exp2f(m - mn);
                m = mn; l *= alpha;
#pragma unroll
                for (int dt = 0; dt < 4; ++dt)
#pragma unroll
                    for (int r = 0; r < 4; ++r) o[dt][r] *= alpha;
            }
            bf16x8 w[4];
            float rs = 0.f;
#pragma unroll
            for (int n = 0; n < 8; ++n) {
                const float p0 = exp2f(sc[n][0] - m), p1 = exp2f(sc[n][1] - m);
                const float p2 = exp2f(sc[n][2] - m), p3 = exp2f(sc[n][3] - m);
                rs += (p0 + p1) + (p2 + p3);
                const int wi = n >> 1, off = (n & 1) * 4;
                w[wi][off + 0] = (bf16_t)p0; w[wi][off + 1] = (bf16_t)p1;
                w[wi][off + 2] = (bf16_t)p2; w[wi][off + 3] = (bf16_t)p3;
            }
            l += rs;
            __builtin_amdgcn_s_setprio(1);
#pragma unroll
            for (int ks = 0; ks < 4; ++ks) {
#pragma unroll
                for (int dt = 0; dt < 4; ++dt) {
                    const bf16x8 vb = *reinterpret_cast<const bf16x8*>(&Vt_lds[cur][dt * 16 + lc][ks * 32 + lg * 8]);
                    o[dt] = __builtin_amdgcn_mfma_f32_16x16x32_bf16(vb, w[ks], o[dt], 0, 0, 0);
                }
            }
            __builtin_amdgcn_s_setprio(0);
            __syncthreads();
        }
        float lr = l;
        lr += __shfl_xor(lr, 16);
        lr += __shfl_xor(lr, 32);
        const float inv = 1.0f / lr;
#pragma unroll
        for (int dt = 0; dt < 4; ++dt) {
            f32x4 val = { o[dt][0] * inv, o[dt][1] * inv, o[dt][2] * inv, o[dt][3] * inv };
            *reinterpret_cast<f32x4*>(Og + bbase + (size_t)qrow * D_H + dt * 16 + lg * 4) = val;
        }
    }
}

extern "C" void kernel_launch(void* const* d_in, const int* in_sizes, int n_in,
                              void* d_out, int out_size, void* d_ws, size_t ws_size,
                              hipStream_t stream)
{
    const float* Q = (const float*)d_in[0];
    const float* K = (const float*)d_in[1];
    const float* V = (const float*)d_in[2];
    float* O = (float*)d_out;

    const size_t need = (OPART_FL + ML_FL) * sizeof(float);   // ~8.25 MB
    if (ws_size >= need) {
        float* Opart = (float*)d_ws;
        float* MLb   = Opart + OPART_FL;
        attn_pcs_kernel<<<dim3(512), dim3(512), 0, stream>>>(Q, K, V, O, Opart, MLb);
        merge_kernel<<<dim3(256), dim3(256), 0, stream>>>(Opart, MLb, O);
    } else {
        attn_pc_kernel<<<dim3(512), dim3(512), 0, stream>>>(Q, K, V, O);
    }
}

// Round 22
// 36.004 us; speedup vs baseline: 1.0448x; 1.0448x over previous
//
#include <hip/hip_runtime.h>

typedef __bf16 bf16_t;
typedef __bf16 bf16x4 __attribute__((ext_vector_type(4)));
typedef __bf16 bf16x8 __attribute__((ext_vector_type(8)));
typedef float  f32x4  __attribute__((ext_vector_type(4)));

#define B_SZ  16
#define L_SEQ 2048
#define D_H   64
#define QB    64
#define KB    128
#define NT128 16                 // L_SEQ / 128
#define TILE_HW (128 * D_H)      // 8192 bf16 per 128-tile image (16 KB)
#define IMG_ELEMS ((size_t)B_SZ * NT128 * TILE_HW)   // per tensor

// softmax is over (S/8); fold log2(e)/8 into Q so MFMA output is in log2 units
#define QSCALE 0.18033688011112043f

#define GLD_LDS16(g, l) __builtin_amdgcn_global_load_lds(                       \
    (const __attribute__((address_space(1))) void*)(g),                         \
    (__attribute__((address_space(3))) void*)(l), 16, 0, 0)

// ---------------- preproc (r12 verbatim): bf16 + transpose(V) + XOR-swizzle images ----
__global__ __launch_bounds__(256)
void preproc_kernel(const float* __restrict__ Kg, const float* __restrict__ Vg,
                    bf16_t* __restrict__ Kimg, bf16_t* __restrict__ Vimg)
{
    const int kt = blockIdx.x, b = blockIdx.y, z = blockIdx.z;   // z = quarter
    const int t  = threadIdx.x;
    const size_t src = (size_t)b * L_SEQ * D_H + (size_t)kt * 128 * D_H;
    bf16_t* ko = Kimg + (size_t)(b * NT128 + kt) * TILE_HW;
    bf16_t* vo = Vimg + (size_t)(b * NT128 + kt) * TILE_HW;

    {
        const int u = z * 256 + t, r = u >> 3, ch = u & 7;
        const float* p = Kg + src + r * 64 + ch * 8;
        const f32x4 a = *reinterpret_cast<const f32x4*>(p);
        const f32x4 c = *reinterpret_cast<const f32x4*>(p + 4);
        bf16x8 kk;
#pragma unroll
        for (int j = 0; j < 4; ++j) { kk[j] = (bf16_t)a[j]; kk[4 + j] = (bf16_t)c[j]; }
        *reinterpret_cast<bf16x8*>(&ko[r * 64 + ((ch ^ (r & 7)) << 3)]) = kk;
    }
    {
        const int d = t & 63, pc = (t >> 6) + z * 4;
        bf16x8 vv;
#pragma unroll
        for (int pw = 0; pw < 8; ++pw) {
            const int pos = pc * 8 + pw;
            const int vkb = ((pos >> 3) & 3) | (((pos >> 2) & 1) << 2) | (((pos >> 5) & 3) << 3);
            const int k   = (vkb << 2) | (pos & 3);
            vv[pw] = (bf16_t)Vg[src + (size_t)k * 64 + d];
        }
        *reinterpret_cast<bf16x8*>(&vo[d * 128 + ((pc ^ (d & 7)) << 3)]) = vv;
    }
}

// ---------------- producer/consumer kernel: pure-DMA producers + r12 consumer engine ----
// r20 scaffold: 512 blocks (balanced qt pairing, 2 batches/XCD), 8 waves each, 2 blocks/CU.
// waves 0-3 (consumers): swizzled-image compute engine, 16 q-rows per wave.
// waves 4-7 (producers): ONLY global_load_lds issue (8 instrs/wave/iter) — zero VALU.
__global__ __launch_bounds__(512, 4)
void attn_pci_kernel(const float* __restrict__ Qg, float* __restrict__ Og,
                     const bf16_t* __restrict__ Kimg, const bf16_t* __restrict__ Vimg)
{
    const int lin  = blockIdx.x;          // 0..511
    const int xcd  = lin & 7;
    const int slot = lin >> 3;            // 0..63
    const int half = slot >> 5;
    const int qi   = slot & 31;
    const int b    = xcd * 2 + half;      // 2 batches per XCD -> images L2-resident
    const int qt   = half ? qi : (31 - qi);

    const int tid  = threadIdx.x;
    const int wave = tid >> 6;            // 0..7
    const int lane = tid & 63;
    const int lg   = lane >> 4;
    const int lc   = lane & 15;
    const int lc7  = lc & 7;

    __shared__ __align__(16) bf16_t K_lds[2][TILE_HW];    // 32 KB (swizzled image layout)
    __shared__ __align__(16) bf16_t Vt_lds[2][TILE_HW];   // 32 KB

    const size_t bbase = (size_t)b * L_SEQ * D_H;
    const bf16_t* kimg = Kimg + (size_t)b * NT128 * TILE_HW;
    const bf16_t* vimg = Vimg + (size_t)b * NT128 * TILE_HW;

    const int nkt = (qt + 2) >> 1;        // number of 128-wide K tiles (last masked)

    if (wave >= 4) {
        // ================= PRODUCER (waves 4-7): pure DMA issue =================
        const int pw = wave - 4;          // 0..3: owns chunks [pw*4, pw*4+4)
        auto stage = [&](int kt, int buf) {
            const bf16_t* ks = kimg + (size_t)kt * TILE_HW;
            const bf16_t* vs = vimg + (size_t)kt * TILE_HW;
#pragma unroll
            for (int i = 0; i < 4; ++i) {
                const int c = pw * 4 + i;                  // chunk 0..15 (512 bf16 = 1 KB)
                GLD_LDS16(ks + c * 512 + lane * 8, &K_lds[buf][c * 512]);
                GLD_LDS16(vs + c * 512 + lane * 8, &Vt_lds[buf][c * 512]);
            }
        };

        stage(0, 0);
        __syncthreads();                                   // drains producer vmcnt: tile 0 ready
        for (int kt = 0; kt < nkt; ++kt) {
            if (kt + 1 < nkt) stage(kt + 1, (kt + 1) & 1);
            __syncthreads();                               // tile kt+1 ready / kt consumed
        }
    } else {
        // ================= CONSUMER (waves 0-3): zero vmem in loop =================
        const int qrow = qt * QB + wave * 16 + lc;
        bf16x8 qa[2];
#pragma unroll
        for (int h = 0; h < 2; ++h) {
            const float* qp = Qg + bbase + (size_t)qrow * D_H + h * 32 + lg * 8;
            const f32x4 f0 = *reinterpret_cast<const f32x4*>(qp);
            const f32x4 f1 = *reinterpret_cast<const f32x4*>(qp + 4);
            bf16x8 a;
#pragma unroll
            for (int j = 0; j < 4; ++j) { a[j] = (bf16_t)(f0[j] * QSCALE); a[4 + j] = (bf16_t)(f1[j] * QSCALE); }
            qa[h] = a;
        }

        f32x4 o[4];
#pragma unroll
        for (int dt = 0; dt < 4; ++dt) o[dt] = (f32x4){0.f, 0.f, 0.f, 0.f};
        float m = -1e30f, l = 0.f;        // per-lane l partial in frame m

        __syncthreads();                                   // tile 0 ready
        for (int kt = 0; kt < nkt; ++kt) {
            const bool last = (kt == nkt - 1);
            const int kb0 = kt * KB;
            const int cur = kt & 1;

            // ---- S^T = K Q^T (log2 units): sc[n][r] = S[k=kb0+n*16+lg*4+r][q=qrow] ----
            f32x4 sc[8];
            __builtin_amdgcn_s_setprio(1);
#pragma unroll
            for (int n = 0; n < 8; ++n) {
                f32x4 acc = (f32x4){0.f, 0.f, 0.f, 0.f};
#pragma unroll
                for (int h = 0; h < 2; ++h) {
                    const int hw = (n * 16 + lc) * 64 + ((((h << 2) | lg) ^ lc7) << 3);
                    const bf16x8 kkb = *reinterpret_cast<const bf16x8*>(&K_lds[cur][hw]);
                    acc = __builtin_amdgcn_mfma_f32_16x16x32_bf16(kkb, qa[h], acc, 0, 0, 0);
                }
                sc[n] = acc;
            }
            __builtin_amdgcn_s_setprio(0);
            if (last) {
#pragma unroll
                for (int n = 0; n < 8; ++n)
#pragma unroll
                    for (int r = 0; r < 4; ++r)
                        if (kb0 + n * 16 + lg * 4 + r > qrow) sc[n][r] = -1e30f;
            }

            // ---- defer-max online softmax (per-lane; cross-lane only on slow path) ----
            float mxp = fmaxf(fmaxf(sc[0][0], sc[0][1]), fmaxf(sc[0][2], sc[0][3]));
#pragma unroll
            for (int n = 1; n < 8; ++n)
                mxp = fmaxf(mxp, fmaxf(fmaxf(sc[n][0], sc[n][1]), fmaxf(sc[n][2], sc[n][3])));
            if (!__all(mxp <= m + 8.0f)) {
                float mx = mxp;
                mx = fmaxf(mx, __shfl_xor(mx, 16));
                mx = fmaxf(mx, __shfl_xor(mx, 32));
                const float mn = fmaxf(m, mx);
                const float alpha = exp2f(m - mn);
                m = mn;
                l *= alpha;
#pragma unroll
                for (int dt = 0; dt < 4; ++dt)
#pragma unroll
                    for (int r = 0; r < 4; ++r) o[dt][r] *= alpha;
            }
            // P packed directly into the PV B-operand layout (phi-permuted V^T image)
            bf16x8 w[4];
            float rs = 0.f;
#pragma unroll
            for (int n = 0; n < 8; ++n) {
                const float p0 = exp2f(sc[n][0] - m), p1 = exp2f(sc[n][1] - m);
                const float p2 = exp2f(sc[n][2] - m), p3 = exp2f(sc[n][3] - m);
                rs += (p0 + p1) + (p2 + p3);
                const int wi = n >> 1, off = (n & 1) * 4;
                w[wi][off + 0] = (bf16_t)p0; w[wi][off + 1] = (bf16_t)p1;
                w[wi][off + 2] = (bf16_t)p2; w[wi][off + 3] = (bf16_t)p3;
            }
            l += rs;

            // ---- O^T += V^T P : P straight from registers, V^T from swizzled LDS ----
            __builtin_amdgcn_s_setprio(1);
#pragma unroll
            for (int ks = 0; ks < 4; ++ks) {
#pragma unroll
                for (int dt = 0; dt < 4; ++dt) {
                    const int hw = (dt * 16 + lc) * 128 + ((((ks << 2) | lg) ^ lc7) << 3);
                    const bf16x8 vb = *reinterpret_cast<const bf16x8*>(&Vt_lds[cur][hw]);
                    o[dt] = __builtin_amdgcn_mfma_f32_16x16x32_bf16(vb, w[ks], o[dt], 0, 0, 0);
                }
            }
            __builtin_amdgcn_s_setprio(0);

            __syncthreads();                               // tile kt consumed / kt+1 ready
        }

        // ---- epilogue: reduce per-lane l, then O = O^T / l ----
        float lr = l;
        lr += __shfl_xor(lr, 16);
        lr += __shfl_xor(lr, 32);
        const float inv = 1.0f / lr;
#pragma unroll
        for (int dt = 0; dt < 4; ++dt) {
            f32x4 val = { o[dt][0] * inv, o[dt][1] * inv, o[dt][2] * inv, o[dt][3] * inv };
            *reinterpret_cast<f32x4*>(Og + bbase + (size_t)qrow * D_H + dt * 16 + lg * 4) = val;
        }
    }
}

// ---------------- fallback: round-20 producer/consumer kernel (no ws needed) ----------------
__global__ __launch_bounds__(512, 4)
void attn_pc_kernel(const float* __restrict__ Qg, const float* __restrict__ Kg,
                    const float* __restrict__ Vg, float* __restrict__ Og)
{
    const int lin  = blockIdx.x;
    const int xcd  = lin & 7;
    const int slot = lin >> 3;
    const int half = slot >> 5;
    const int qi   = slot & 31;
    const int b    = xcd * 2 + half;
    const int qt   = half ? qi : (31 - qi);

    const int tid  = threadIdx.x;
    const int wave = tid >> 6;
    const int lane = tid & 63;
    const int lg   = lane >> 4;
    const int lc   = lane & 15;

    __shared__ __align__(16) bf16_t K_lds[2][KB][72];
    __shared__ __align__(16) bf16_t Vt_lds[2][D_H][136];

    const size_t bbase = (size_t)b * L_SEQ * D_H;
    const int nkt = (qt + 2) >> 1;

    if (wave >= 4) {
        const int pt   = tid - 256;
        const int vkb  = pt & 31;
        const int vdg  = pt >> 5;
        const int vpos = ((vkb >> 3) << 5) + ((vkb & 3) << 3) + (((vkb >> 2) & 1) << 2);

        f32x4 kreg[8], vreg[8];
        auto issueK = [&](int kt) {
            const int kbase = kt * KB;
#pragma unroll
            for (int i = 0; i < 8; ++i) {
                const int f = i * 256 + pt;
                const int r = f >> 4, c4 = (f & 15) * 4;
                kreg[i] = *reinterpret_cast<const f32x4*>(Kg + bbase + (size_t)(kbase + r) * D_H + c4);
            }
        };
        auto issueV = [&](int kt) {
            const int kbase = kt * KB;
#pragma unroll
            for (int d2 = 0; d2 < 2; ++d2)
#pragma unroll
                for (int i = 0; i < 4; ++i)
                    vreg[d2 * 4 + i] = *reinterpret_cast<const f32x4*>(
                        Vg + bbase + (size_t)(kbase + vkb * 4 + i) * D_H + (vdg + d2 * 8) * 4);
        };
        auto writeK = [&](int buf) {
#pragma unroll
            for (int i = 0; i < 8; ++i) {
                const int f = i * 256 + pt;
                const int r = f >> 4, c4 = (f & 15) * 4;
                bf16x4 k4 = { (bf16_t)kreg[i][0], (bf16_t)kreg[i][1], (bf16_t)kreg[i][2], (bf16_t)kreg[i][3] };
                *reinterpret_cast<bf16x4*>(&K_lds[buf][r][c4]) = k4;
            }
        };
        auto writeV = [&](int buf) {
#pragma unroll
            for (int d2 = 0; d2 < 2; ++d2) {
                const int db = vdg + d2 * 8;
#pragma unroll
                for (int j = 0; j < 4; ++j) {
                    bf16x4 cj = { (bf16_t)vreg[d2 * 4 + 0][j], (bf16_t)vreg[d2 * 4 + 1][j],
                                  (bf16_t)vreg[d2 * 4 + 2][j], (bf16_t)vreg[d2 * 4 + 3][j] };
                    *reinterpret_cast<bf16x4*>(&Vt_lds[buf][db * 4 + j][vpos]) = cj;
                }
            }
        };

        issueK(0); issueV(0); writeK(0); writeV(0);
        __syncthreads();
        for (int kt = 0; kt < nkt; ++kt) {
            if (kt + 1 < nkt) {
                issueK(kt + 1); issueV(kt + 1);
                writeK((kt + 1) & 1); writeV((kt + 1) & 1);
            }
            __syncthreads();
        }
    } else {
        const int qrow = qt * QB + wave * 16 + lc;
        bf16x8 qa[2];
#pragma unroll
        for (int h = 0; h < 2; ++h) {
            const float* qp = Qg + bbase + (size_t)qrow * D_H + h * 32 + lg * 8;
            const f32x4 f0 = *reinterpret_cast<const f32x4*>(qp);
            const f32x4 f1 = *reinterpret_cast<const f32x4*>(qp + 4);
            bf16x8 a;
#pragma unroll
            for (int j = 0; j < 4; ++j) { a[j] = (bf16_t)(f0[j] * QSCALE); a[4 + j] = (bf16_t)(f1[j] * QSCALE); }
            qa[h] = a;
        }
        f32x4 o[4];
#pragma unroll
        for (int dt = 0; dt < 4; ++dt) o[dt] = (f32x4){0.f, 0.f, 0.f, 0.f};
        float m = -1e30f, l = 0.f;

        __syncthreads();
        for (int kt = 0; kt < nkt; ++kt) {
            const bool last = (kt == nkt - 1);
            const int kbase = kt * KB;
            const int cur   = kt & 1;
            f32x4 sc[8];
            __builtin_amdgcn_s_setprio(1);
#pragma unroll
            for (int n = 0; n < 8; ++n) {
                f32x4 acc = (f32x4){0.f, 0.f, 0.f, 0.f};
#pragma unroll
                for (int h = 0; h < 2; ++h) {
                    const bf16x8 kb = *reinterpret_cast<const bf16x8*>(&K_lds[cur][n * 16 + lc][h * 32 + lg * 8]);
                    acc = __builtin_amdgcn_mfma_f32_16x16x32_bf16(kb, qa[h], acc, 0, 0, 0);
                }
                sc[n] = acc;
            }
            __builtin_amdgcn_s_setprio(0);
            if (last) {
#pragma unroll
                for (int n = 0; n < 8; ++n)
#pragma unroll
                    for (int r = 0; r < 4; ++r)
                        if (kbase + n * 16 + lg * 4 + r > qrow) sc[n][r] = -1e30f;
            }
            float mxp = fmaxf(fmaxf(sc[0][0], sc[0][1]), fmaxf(sc[0][2], sc[0][3]));
#pragma unroll
            for (int n = 1; n < 8; ++n)
                mxp = fmaxf(mxp, fmaxf(fmaxf(sc[n][0], sc[n][1]), fmaxf(sc[n][2], sc[n][3])));
            if (!__all(mxp <= m + 8.0f)) {
                float mx = mxp;
                mx = fmaxf(mx, __shfl_xor(mx, 16));
                mx = fmaxf(mx, __shfl_xor(mx, 32));
                const float mn = fmaxf(m, mx);
                const float alpha = exp2f(m - mn);
                m = mn; l *= alpha;
#pragma unroll
                for (int dt = 0; dt < 4; ++dt)
#pragma unroll
                    for (int r = 0; r < 4; ++r) o[dt][r] *= alpha;
            }
            bf16x8 w[4];
            float rs = 0.f;
#pragma unroll
            for (int n = 0; n < 8; ++n) {
                const float p0 = exp2f(sc[n][0] - m), p1 = exp2f(sc[n][1] - m);
                const float p2 = exp2f(sc[n][2] - m), p3 = exp2f(sc[n][3] - m);
                rs += (p0 + p1) + (p2 + p3);
                const int wi = n >> 1, off = (n & 1) * 4;
                w[wi][off + 0] = (bf16_t)p0; w[wi][off + 1] = (bf16_t)p1;
                w[wi][off + 2] = (bf16_t)p2; w[wi][off + 3] = (bf16_t)p3;
            }
            l += rs;
            __builtin_amdgcn_s_setprio(1);
#pragma unroll
            for (int ks = 0; ks < 4; ++ks) {
#pragma unroll
                for (int dt = 0; dt < 4; ++dt) {
                    const bf16x8 vb = *reinterpret_cast<const bf16x8*>(&Vt_lds[cur][dt * 16 + lc][ks * 32 + lg * 8]);
                    o[dt] = __builtin_amdgcn_mfma_f32_16x16x32_bf16(vb, w[ks], o[dt], 0, 0, 0);
                }
            }
            __builtin_amdgcn_s_setprio(0);
            __syncthreads();
        }
        float lr = l;
        lr += __shfl_xor(lr, 16);
        lr += __shfl_xor(lr, 32);
        const float inv = 1.0f / lr;
#pragma unroll
        for (int dt = 0; dt < 4; ++dt) {
            f32x4 val = { o[dt][0] * inv, o[dt][1] * inv, o[dt][2] * inv, o[dt][3] * inv };
            *reinterpret_cast<f32x4*>(Og + bbase + (size_t)qrow * D_H + dt * 16 + lg * 4) = val;
        }
    }
}

extern "C" void kernel_launch(void* const* d_in, const int* in_sizes, int n_in,
                              void* d_out, int out_size, void* d_ws, size_t ws_size,
                              hipStream_t stream)
{
    const float* Q = (const float*)d_in[0];
    const float* K = (const float*)d_in[1];
    const float* V = (const float*)d_in[2];
    float* O = (float*)d_out;

    const size_t need = 2 * IMG_ELEMS * sizeof(bf16_t);   // 8 MB
    if (ws_size >= need) {
        bf16_t* Kimg = (bf16_t*)d_ws;
        bf16_t* Vimg = Kimg + IMG_ELEMS;
        preproc_kernel<<<dim3(NT128, B_SZ, 4), dim3(256), 0, stream>>>(K, V, Kimg, Vimg);
        attn_pci_kernel<<<dim3(512), dim3(512), 0, stream>>>(Q, O, Kimg, Vimg);
    } else {
        attn_pc_kernel<<<dim3(512), dim3(512), 0, stream>>>(Q, K, V, O);
    }
}

// Round 23
// 34.152 us; speedup vs baseline: 1.1015x; 1.0542x over previous
//
#include <hip/hip_runtime.h>

typedef __bf16 bf16_t;
typedef __bf16 bf16x4 __attribute__((ext_vector_type(4)));
typedef __bf16 bf16x8 __attribute__((ext_vector_type(8)));
typedef float  f32x4  __attribute__((ext_vector_type(4)));

#define B_SZ  16
#define L_SEQ 2048
#define D_H   64
#define QB    64
#define KB    128
#define NQT   (L_SEQ / QB)   // 32

// softmax is over (S/8); fold log2(e)/8 into Q so MFMA output is in log2 units
#define QSCALE 0.18033688011112043f

// ---------------- barrier-free producer/consumer kernel ----------------
// r20 scaffold: 512 blocks (balanced qt pairing, 2 batches/XCD), 8 waves, 2 blocks/CU.
// waves 0-3: consumers (r20 compute engine). waves 4-7: producers (r20 staging engine).
// NO __syncthreads in the main loop: LDS generation counters instead.
//   tile j lives in buf=j&1, fill f(j)=j/2+1.
//   producer: wait done[buf] >= 4*(j/2)   -> stage -> lgkm fence -> ready[buf] += 1 (lane0)
//   consumer: wait ready[buf] >= 4*f(j)   -> compute -> lgkm fence -> done[buf] += 1 (lane0)
__global__ __launch_bounds__(512, 4)
void attn_pcf_kernel(const float* __restrict__ Qg, const float* __restrict__ Kg,
                     const float* __restrict__ Vg, float* __restrict__ Og)
{
    const int lin  = blockIdx.x;          // 0..511
    const int xcd  = lin & 7;
    const int slot = lin >> 3;            // 0..63
    const int half = slot >> 5;
    const int qi   = slot & 31;
    const int b    = xcd * 2 + half;      // 2 batches per XCD -> K/V L2-resident
    const int qt   = half ? qi : (31 - qi);

    const int tid  = threadIdx.x;
    const int wave = tid >> 6;            // 0..7
    const int lane = tid & 63;
    const int lg   = lane >> 4;
    const int lc   = lane & 15;

    __shared__ __align__(16) bf16_t K_lds[2][KB][72];      // 36 KB
    __shared__ __align__(16) bf16_t Vt_lds[2][D_H][136];   // 34 KB
    __shared__ int ready_cnt[2];
    __shared__ int done_cnt[2];

    if (tid == 0) { ready_cnt[0] = ready_cnt[1] = 0; done_cnt[0] = done_cnt[1] = 0; }
    __syncthreads();                       // the only block-wide barrier

    const size_t bbase = (size_t)b * L_SEQ * D_H;
    const int nkt = (qt + 2) >> 1;         // number of 128-wide K tiles (last masked)

    auto pollGE = [&](volatile int* p, int target) {
        while (*p < target) __builtin_amdgcn_s_sleep(2);
    };

    if (wave >= 4) {
        // ================= PRODUCER (waves 4-7, 256 threads) =================
        const int pt   = tid - 256;
        const int vkb  = pt & 31;
        const int vdg  = pt >> 5;
        const int vpos = ((vkb >> 3) << 5) + ((vkb & 3) << 3) + (((vkb >> 2) & 1) << 2);

        f32x4 kreg[8], vreg[8];

        auto issueK = [&](int kt) {
            const int kbase = kt * KB;
#pragma unroll
            for (int i = 0; i < 8; ++i) {
                const int f = i * 256 + pt;
                const int r = f >> 4, c4 = (f & 15) * 4;
                kreg[i] = *reinterpret_cast<const f32x4*>(Kg + bbase + (size_t)(kbase + r) * D_H + c4);
            }
        };
        auto issueV = [&](int kt) {
            const int kbase = kt * KB;
#pragma unroll
            for (int d2 = 0; d2 < 2; ++d2)
#pragma unroll
                for (int i = 0; i < 4; ++i)
                    vreg[d2 * 4 + i] = *reinterpret_cast<const f32x4*>(
                        Vg + bbase + (size_t)(kbase + vkb * 4 + i) * D_H + (vdg + d2 * 8) * 4);
        };
        auto writeK = [&](int buf) {
#pragma unroll
            for (int i = 0; i < 8; ++i) {
                const int f = i * 256 + pt;
                const int r = f >> 4, c4 = (f & 15) * 4;
                bf16x4 k4 = { (bf16_t)kreg[i][0], (bf16_t)kreg[i][1], (bf16_t)kreg[i][2], (bf16_t)kreg[i][3] };
                *reinterpret_cast<bf16x4*>(&K_lds[buf][r][c4]) = k4;
            }
        };
        auto writeV = [&](int buf) {
#pragma unroll
            for (int d2 = 0; d2 < 2; ++d2) {
                const int db = vdg + d2 * 8;
#pragma unroll
                for (int j = 0; j < 4; ++j) {
                    bf16x4 cj = { (bf16_t)vreg[d2 * 4 + 0][j], (bf16_t)vreg[d2 * 4 + 1][j],
                                  (bf16_t)vreg[d2 * 4 + 2][j], (bf16_t)vreg[d2 * 4 + 3][j] };
                    *reinterpret_cast<bf16x4*>(&Vt_lds[buf][db * 4 + j][vpos]) = cj;
                }
            }
        };

        for (int j = 0; j < nkt; ++j) {
            const int buf = j & 1;
            issueK(j); issueV(j);                          // loads in flight during wait
            if (j >= 2) pollGE((volatile int*)&done_cnt[buf], 4 * (j >> 1));
            writeK(buf); writeV(buf);
            // flag AFTER data: fence compiler + wave-level DS completion
            asm volatile("s_waitcnt lgkmcnt(0)" ::: "memory");
            __builtin_amdgcn_sched_barrier(0);
            if (lane == 0) atomicAdd(&ready_cnt[buf], 1);
        }
    } else {
        // ================= CONSUMER (waves 0-3) =================
        const int qrow = qt * QB + wave * 16 + lc;
        bf16x8 qa[2];
#pragma unroll
        for (int h = 0; h < 2; ++h) {
            const float* qp = Qg + bbase + (size_t)qrow * D_H + h * 32 + lg * 8;
            const f32x4 f0 = *reinterpret_cast<const f32x4*>(qp);
            const f32x4 f1 = *reinterpret_cast<const f32x4*>(qp + 4);
            bf16x8 a;
#pragma unroll
            for (int j = 0; j < 4; ++j) { a[j] = (bf16_t)(f0[j] * QSCALE); a[4 + j] = (bf16_t)(f1[j] * QSCALE); }
            qa[h] = a;
        }

        f32x4 o[4];
#pragma unroll
        for (int dt = 0; dt < 4; ++dt) o[dt] = (f32x4){0.f, 0.f, 0.f, 0.f};
        float m = -1e30f, l = 0.f;        // per-lane l partial in frame m

        for (int kt = 0; kt < nkt; ++kt) {
            const bool last = (kt == nkt - 1);
            const int kbase = kt * KB;
            const int cur   = kt & 1;

            pollGE((volatile int*)&ready_cnt[cur], 4 * ((kt >> 1) + 1));

            // ---- S^T = K Q^T (log2 units): sc[n][r] = S[k=kbase+n*16+lg*4+r][q=qrow] ----
            f32x4 sc[8];
            __builtin_amdgcn_s_setprio(1);
#pragma unroll
            for (int n = 0; n < 8; ++n) {
                f32x4 acc = (f32x4){0.f, 0.f, 0.f, 0.f};
#pragma unroll
                for (int h = 0; h < 2; ++h) {
                    const bf16x8 kb = *reinterpret_cast<const bf16x8*>(&K_lds[cur][n * 16 + lc][h * 32 + lg * 8]);
                    acc = __builtin_amdgcn_mfma_f32_16x16x32_bf16(kb, qa[h], acc, 0, 0, 0);
                }
                sc[n] = acc;
            }
            __builtin_amdgcn_s_setprio(0);
            if (last) {
#pragma unroll
                for (int n = 0; n < 8; ++n)
#pragma unroll
                    for (int r = 0; r < 4; ++r)
                        if (kbase + n * 16 + lg * 4 + r > qrow) sc[n][r] = -1e30f;
            }

            // ---- defer-max online softmax (per-lane; cross-lane only on slow path) ----
            float mxp = fmaxf(fmaxf(sc[0][0], sc[0][1]), fmaxf(sc[0][2], sc[0][3]));
#pragma unroll
            for (int n = 1; n < 8; ++n)
                mxp = fmaxf(mxp, fmaxf(fmaxf(sc[n][0], sc[n][1]), fmaxf(sc[n][2], sc[n][3])));
            if (!__all(mxp <= m + 8.0f)) {
                float mx = mxp;
                mx = fmaxf(mx, __shfl_xor(mx, 16));
                mx = fmaxf(mx, __shfl_xor(mx, 32));
                const float mn = fmaxf(m, mx);
                const float alpha = exp2f(m - mn);
                m = mn;
                l *= alpha;
#pragma unroll
                for (int dt = 0; dt < 4; ++dt)
#pragma unroll
                    for (int r = 0; r < 4; ++r) o[dt][r] *= alpha;
            }
            // P packed directly into the PV B-operand layout (phi-permuted V^T)
            bf16x8 w[4];
            float rs = 0.f;
#pragma unroll
            for (int n = 0; n < 8; ++n) {
                const float p0 = exp2f(sc[n][0] - m), p1 = exp2f(sc[n][1] - m);
                const float p2 = exp2f(sc[n][2] - m), p3 = exp2f(sc[n][3] - m);
                rs += (p0 + p1) + (p2 + p3);
                const int wi = n >> 1, off = (n & 1) * 4;
                w[wi][off + 0] = (bf16_t)p0; w[wi][off + 1] = (bf16_t)p1;
                w[wi][off + 2] = (bf16_t)p2; w[wi][off + 3] = (bf16_t)p3;
            }
            l += rs;

            // ---- O^T += V^T P : P straight from registers ----
            __builtin_amdgcn_s_setprio(1);
#pragma unroll
            for (int ks = 0; ks < 4; ++ks) {
#pragma unroll
                for (int dt = 0; dt < 4; ++dt) {
                    const bf16x8 vb = *reinterpret_cast<const bf16x8*>(&Vt_lds[cur][dt * 16 + lc][ks * 32 + lg * 8]);
                    o[dt] = __builtin_amdgcn_mfma_f32_16x16x32_bf16(vb, w[ks], o[dt], 0, 0, 0);
                }
            }
            __builtin_amdgcn_s_setprio(0);

            // signal AFTER last LDS read of this tile
            asm volatile("s_waitcnt lgkmcnt(0)" ::: "memory");
            __builtin_amdgcn_sched_barrier(0);
            if (lane == 0) atomicAdd(&done_cnt[cur], 1);
        }

        // ---- epilogue: reduce per-lane l, then O = O^T / l ----
        float lr = l;
        lr += __shfl_xor(lr, 16);
        lr += __shfl_xor(lr, 32);
        const float inv = 1.0f / lr;
#pragma unroll
        for (int dt = 0; dt < 4; ++dt) {
            f32x4 val = { o[dt][0] * inv, o[dt][1] * inv, o[dt][2] * inv, o[dt][3] * inv };
            *reinterpret_cast<f32x4*>(Og + bbase + (size_t)qrow * D_H + dt * 16 + lg * 4) = val;
        }
    }
}

extern "C" void kernel_launch(void* const* d_in, const int* in_sizes, int n_in,
                              void* d_out, int out_size, void* d_ws, size_t ws_size,
                              hipStream_t stream)
{
    const float* Q = (const float*)d_in[0];
    const float* K = (const float*)d_in[1];
    const float* V = (const float*)d_in[2];
    float* O = (float*)d_out;
    attn_pcf_kernel<<<dim3(NQT * B_SZ), dim3(512), 0, stream>>>(Q, K, V, O);
}